// Round 4
// baseline (351.802 us; speedup 1.0000x reference)
//
#include <hip/hip_runtime.h>

// InteractLayer via bf16 MFMA. B=16384, F=32, D=64, H=64 (2 heads x 32).
// R3: R2 structure (LDS 19.4 KB, 2 barriers, reg-resident residual, X A-frags
// direct from global) but with SOFTWARE RNE bf16 conversion everywhere --
// the v_cvt_pk_bf16_f32 inline asm in R2 produced full-magnitude errors
// (suspected reversed pack order / unverified opcode). Correctness first.

constexpr int kF = 32, kD = 64, kH = 64;

constexpr int QS = 72;   // s_q / s_k row stride (shorts): 144B rows, 16B-aligned
constexpr int VS = 40;   // s_vt row stride: 80B rows
constexpr int PS = 40;   // s_p  row stride

using short8  = __attribute__((ext_vector_type(8))) short;
using float4v = __attribute__((ext_vector_type(4))) float;

__device__ __forceinline__ unsigned short f2bf_rne(float x) {
    unsigned u = __float_as_uint(x);
    u += 0x7FFF + ((u >> 16) & 1);
    return (unsigned short)(u >> 16);
}
__device__ __forceinline__ unsigned pk_bf16(float lo, float hi) {   // lo -> bits 15:0
    return (unsigned)f2bf_rne(lo) | ((unsigned)f2bf_rne(hi) << 16);
}

__global__ void wprep_kernel(const float* __restrict__ Wq, const float* __restrict__ Wk,
                             const float* __restrict__ Wv, const float* __restrict__ Wr,
                             unsigned short* __restrict__ wt) {
    const int m = blockIdx.x;               // 0..3 : Q,K,V,R
    const float* __restrict__ W = (m == 0) ? Wq : (m == 1) ? Wk : (m == 2) ? Wv : Wr;
    for (int i = threadIdx.x; i < kD * kH; i += blockDim.x) {
        const int e = i >> 6, d = i & 63;
        wt[m * kD * kH + e * kD + d] = f2bf_rne(W[d * kH + e]);   // Wt[e][d]
    }
}

__global__ __launch_bounds__(256, 4)
void interact_mfma(const float* __restrict__ X, const unsigned short* __restrict__ Wt,
                   float* __restrict__ out)
{
    __shared__ __align__(16) unsigned short s_q [kF * QS];      // 4608 B
    __shared__ __align__(16) unsigned short s_k [kF * QS];      // 4608 B
    __shared__ __align__(16) unsigned short s_vt[kH * VS];      // 5120 B  Vt[e][token]
    __shared__ __align__(16) unsigned short s_p [2 * kF * PS];  // 5120 B  P[h][q][k] unnorm

    const int t    = threadIdx.x;
    const int w    = t >> 6;        // wave 0..3
    const int lane = t & 63;
    const int quad = lane >> 4;
    const int l    = lane & 15;
    const int b    = blockIdx.x;

    const int h   = w >> 1;         // this wave's head (phases 2/3)
    const int mtw = w & 1;          // this wave's row-block (phases 2/3, R slice)

    const float* __restrict__ Xb = X + (size_t)b * (kF * kD);

    // ---- X A-fragments straight from global (bf16 in regs) ----
    // A[m = 16*mt + l][k = 32*ks + quad*8 + j]
    auto load_xa = [&](int mt, int ks) -> short8 {
        const float* p = Xb + (16 * mt + l) * kD + 32 * ks + quad * 8;
        const float4 a = *reinterpret_cast<const float4*>(p);
        const float4 c = *reinterpret_cast<const float4*>(p + 4);
        union { unsigned u[4]; short8 v; } r;
        r.u[0] = pk_bf16(a.x, a.y);
        r.u[1] = pk_bf16(a.z, a.w);
        r.u[2] = pk_bf16(c.x, c.y);
        r.u[3] = pk_bf16(c.z, c.w);
        return r.v;
    };

    // ---- R slice: tiles (mtw, nt=2h) and (mtw, 2h+1), f32 in regs ----
    short8 xa_own[2];               // A-frags for rows 16*mtw.., ks=0,1
    xa_own[0] = load_xa(mtw, 0);
    xa_own[1] = load_xa(mtw, 1);

    float4v racc[2];
    racc[0] = (float4v){0.f, 0.f, 0.f, 0.f};
    racc[1] = (float4v){0.f, 0.f, 0.f, 0.f};
    {
        const unsigned short* __restrict__ wtr = Wt + 3 * (kD * kH);
        #pragma unroll
        for (int i = 0; i < 2; ++i) {
            const int nt = 2 * h + i;
            #pragma unroll
            for (int ks = 0; ks < 2; ++ks) {
                const short8 rb = *reinterpret_cast<const short8*>(
                    wtr + (16 * nt + l) * kD + 32 * ks + quad * 8);
                racc[i] = __builtin_amdgcn_mfma_f32_16x16x32_bf16(xa_own[ks], rb, racc[i], 0, 0, 0);
            }
        }
    }

    // ---- phase 1: projections. w0=Q, w1=K, w2=V(rows 0-15), w3=V(rows 16-31) ----
    if (w < 2) {
        // full 32x64 projection of Q (w0) or K (w1)
        const unsigned short* __restrict__ wtm = Wt + w * (kD * kH);
        short8 xa[2][2];
        #pragma unroll
        for (int ks = 0; ks < 2; ++ks) xa[mtw][ks] = xa_own[ks];
        #pragma unroll
        for (int ks = 0; ks < 2; ++ks) xa[1 - mtw][ks] = load_xa(1 - mtw, ks);

        float4v acc[2][4];
        #pragma unroll
        for (int mt = 0; mt < 2; ++mt)
            #pragma unroll
            for (int nt = 0; nt < 4; ++nt)
                acc[mt][nt] = (float4v){0.f, 0.f, 0.f, 0.f};

        #pragma unroll
        for (int nt = 0; nt < 4; ++nt) {
            #pragma unroll
            for (int ks = 0; ks < 2; ++ks) {
                const short8 bf = *reinterpret_cast<const short8*>(
                    wtm + (16 * nt + l) * kD + 32 * ks + quad * 8);
                #pragma unroll
                for (int mt = 0; mt < 2; ++mt)
                    acc[mt][nt] = __builtin_amdgcn_mfma_f32_16x16x32_bf16(xa[mt][ks], bf, acc[mt][nt], 0, 0, 0);
            }
        }

        unsigned short* __restrict__ dst = (w == 0) ? s_q : s_k;
        #pragma unroll
        for (int mt = 0; mt < 2; ++mt)
            #pragma unroll
            for (int nt = 0; nt < 4; ++nt)
                #pragma unroll
                for (int r = 0; r < 4; ++r)
                    dst[(16 * mt + quad * 4 + r) * QS + 16 * nt + l] = f2bf_rne(acc[mt][nt][r]);
    } else {
        // half of V: rows 16*mtw .. +15
        const unsigned short* __restrict__ wtm = Wt + 2 * (kD * kH);
        float4v acc[4];
        #pragma unroll
        for (int nt = 0; nt < 4; ++nt) acc[nt] = (float4v){0.f, 0.f, 0.f, 0.f};

        #pragma unroll
        for (int nt = 0; nt < 4; ++nt)
            #pragma unroll
            for (int ks = 0; ks < 2; ++ks) {
                const short8 bf = *reinterpret_cast<const short8*>(
                    wtm + (16 * nt + l) * kD + 32 * ks + quad * 8);
                acc[nt] = __builtin_amdgcn_mfma_f32_16x16x32_bf16(xa_own[ks], bf, acc[nt], 0, 0, 0);
            }

        // store transposed: Vt[e = 16*nt + l][token = 16*mtw + quad*4 + r]
        #pragma unroll
        for (int nt = 0; nt < 4; ++nt) {
            unsigned* dst = reinterpret_cast<unsigned*>(
                &s_vt[(16 * nt + l) * VS + 16 * mtw + quad * 4]);
            dst[0] = pk_bf16(acc[nt][0], acc[nt][1]);
            dst[1] = pk_bf16(acc[nt][2], acc[nt][3]);
        }
    }
    __syncthreads();

    // ---- phase 2: scores + in-register softmax; wave = (head h, row-block mtw) ----
    float inv[4];
    {
        const short8 qa =
            *reinterpret_cast<const short8*>(&s_q[(16 * mtw + l) * QS + 32 * h + quad * 8]);
        const short8 kb0 =
            *reinterpret_cast<const short8*>(&s_k[l * QS + 32 * h + quad * 8]);
        const short8 kb1 =
            *reinterpret_cast<const short8*>(&s_k[(16 + l) * QS + 32 * h + quad * 8]);

        float4v s0 = (float4v){0.f, 0.f, 0.f, 0.f};
        float4v s1 = (float4v){0.f, 0.f, 0.f, 0.f};
        s0 = __builtin_amdgcn_mfma_f32_16x16x32_bf16(qa, kb0, s0, 0, 0, 0);
        s1 = __builtin_amdgcn_mfma_f32_16x16x32_bf16(qa, kb1, s1, 0, 0, 0);

        #pragma unroll
        for (int r = 0; r < 4; ++r) {
            float m = fmaxf(s0[r], s1[r]);
            #pragma unroll
            for (int d = 1; d < 16; d <<= 1) m = fmaxf(m, __shfl_xor(m, d));
            const float e0 = __expf(s0[r] - m);
            const float e1 = __expf(s1[r] - m);
            float sum = e0 + e1;
            #pragma unroll
            for (int d = 1; d < 16; d <<= 1) sum += __shfl_xor(sum, d);
            inv[r] = 1.0f / sum;
            const int row = h * kF + 16 * mtw + quad * 4 + r;
            s_p[row * PS + l]      = f2bf_rne(e0);
            s_p[row * PS + 16 + l] = f2bf_rne(e1);
        }
    }
    __syncthreads();

    // ---- phase 3: O_h = P_h @ V_h, + residual (regs), relu, store ----
    {
        const short8 pa =
            *reinterpret_cast<const short8*>(&s_p[(h * kF + 16 * mtw + l) * PS + quad * 8]);
        const short8 vb0 =
            *reinterpret_cast<const short8*>(&s_vt[(32 * h + l) * VS + quad * 8]);
        const short8 vb1 =
            *reinterpret_cast<const short8*>(&s_vt[(32 * h + 16 + l) * VS + quad * 8]);

        float4v o0 = (float4v){0.f, 0.f, 0.f, 0.f};
        float4v o1 = (float4v){0.f, 0.f, 0.f, 0.f};
        o0 = __builtin_amdgcn_mfma_f32_16x16x32_bf16(pa, vb0, o0, 0, 0, 0);
        o1 = __builtin_amdgcn_mfma_f32_16x16x32_bf16(pa, vb1, o1, 0, 0, 0);

        float* __restrict__ Ob = out + (size_t)b * (kF * kH);
        #pragma unroll
        for (int r = 0; r < 4; ++r) {
            const int f = 16 * mtw + quad * 4 + r;
            Ob[f * kH + 32 * h + l]      = fmaxf(o0[r] * inv[r] + racc[0][r], 0.0f);
            Ob[f * kH + 32 * h + 16 + l] = fmaxf(o1[r] * inv[r] + racc[1][r], 0.0f);
        }
    }
}

extern "C" void kernel_launch(void* const* d_in, const int* in_sizes, int n_in,
                              void* d_out, int out_size, void* d_ws, size_t ws_size,
                              hipStream_t stream) {
    const float* X  = (const float*)d_in[0];
    const float* Wq = (const float*)d_in[1];
    const float* Wk = (const float*)d_in[2];
    const float* Wv = (const float*)d_in[3];
    const float* Wr = (const float*)d_in[4];
    float* out = (float*)d_out;
    unsigned short* wt = (unsigned short*)d_ws;   // 4*64*64*2 = 32 KiB

    wprep_kernel<<<4, 256, 0, stream>>>(Wq, Wk, Wv, Wr, wt);

    const int B = in_sizes[0] / (kF * kD);        // 16384
    interact_mfma<<<B, 256, 0, stream>>>(X, wt, out);
}